// Round 2
// baseline (920.084 us; speedup 1.0000x reference)
//
#include <hip/hip_runtime.h>
#include <math.h>

// ---- problem constants ----
#define T_TOK   16384
#define DMODEL  1024
#define DFF     4096
#define NEXP    8
#define CAPACITY 3277            // ceil(16384*1.6/8)
#define CAP_PAD  3328            // ceil(CAPACITY/128)*128

typedef unsigned short u16;
typedef __attribute__((ext_vector_type(8))) __bf16 bf16x8;
typedef __attribute__((ext_vector_type(4))) float  f32x4;

// ---- workspace layout (bytes). Total ~313 MB. ----
#define W1T_OFF   0ull                         // 8*4096*1024*2 = 67108864   bf16 [E][DFF][D]  (B^T for GEMM1)
#define W2T_OFF   67108864ull                  // 67108864                   bf16 [E][D][DFF]  (B^T for GEMM2)
#define XG_OFF    134217728ull                 // 17408*1024*2 = 35651584    bf16 gathered x rows
#define H_OFF     169869312ull                 // 17408*4096*2 = 142606336   bf16 hidden
#define TOPK_OFF  312475648ull                 // 16384*2*4 = 131072
#define CCNT_OFF  312606720ull                 // 128*8*4      (zeroed)
#define CBASE_OFF 312610816ull                 // 128*8*4
#define LISTS_OFF 312614912ull                 // 8*3328*4 = 106496
#define CNT_OFF   312721408ull                 // 8*4          (zeroed)
#define OFFS_OFF  312721472ull                 // 9*4
#define PCNT_OFF  312721536ull                 // 8*4
#define ZERO_SPAN (312721600ull - CCNT_OFF)    // one memset covers ccnt..pcnt

__device__ __forceinline__ u16 f2bf(float x) {   // round-to-nearest-even f32->bf16
  union { float f; unsigned u; } v; v.f = x;
  unsigned r = v.u + 0x7fffu + ((v.u >> 16) & 1u);
  return (u16)(r >> 16);
}

__device__ __forceinline__ void async_cp16(const void* g, void* l) {
  // global -> LDS direct, 16B/lane. LDS dest is wave-uniform base + lane*16.
  __builtin_amdgcn_global_load_lds((const __attribute__((address_space(1))) void*)g,
                                   (__attribute__((address_space(3))) void*)l,
                                   16, 0, 0);
}

// ---- K1: fp32->bf16 transpose-convert, 64x64 tiles, vectorized both sides.
// bid < 8192 : w1 [E][1024][4096] -> w1t [E][4096][1024]
// bid >= 8192: w2 [E][4096][1024] -> w2t [E][1024][4096]
__global__ __launch_bounds__(256) void transpose_cvt64(const float* __restrict__ w1,
    u16* __restrict__ w1t, const float* __restrict__ w2, u16* __restrict__ w2t) {
  int bid = blockIdx.x;
  const float* src; u16* dst; int R, C;
  if (bid < 8192) { src = w1; dst = w1t; R = 1024; C = 4096; }
  else            { src = w2; dst = w2t; R = 4096; C = 1024; bid -= 8192; }
  int tilesC = C >> 6;
  int per_e = (R >> 6) * tilesC;
  int e = bid / per_e, rem = bid % per_e;
  int rt = rem / tilesC, ct = rem % tilesC;
  const float* s = src + (size_t)e*R*C + (size_t)(rt*64)*C + ct*64;
  u16* d = dst + (size_t)e*R*C + (size_t)(ct*64)*R + rt*64;
  __shared__ float tile[64][65];
  int t = threadIdx.x, r0 = t >> 4, c4 = (t & 15) * 4;
#pragma unroll
  for (int i = 0; i < 4; ++i) {
    int row = r0 + i*16;
    float4 v = *(const float4*)(s + (size_t)row*C + c4);
    tile[row][c4] = v.x; tile[row][c4+1] = v.y; tile[row][c4+2] = v.z; tile[row][c4+3] = v.w;
  }
  __syncthreads();
#pragma unroll
  for (int k = 0; k < 4; ++k) {
    int q = k*256 + t;
    int c = q >> 4, g = q & 15;
    ushort4 o;
    o.x = f2bf(tile[g*4+0][c]); o.y = f2bf(tile[g*4+1][c]);
    o.z = f2bf(tile[g*4+2][c]); o.w = f2bf(tile[g*4+3][c]);
    *(ushort4*)(d + (size_t)c*R + g*4) = o;
  }
}

// ---- K2: router logits + noise, top-2 (fp64 accum), fused chunk counts ----
__global__ __launch_bounds__(256) void router_topk(const float* __restrict__ x,
    const float* __restrict__ rw, const float* __restrict__ rb,
    const float* __restrict__ noise, int* __restrict__ topk, int* __restrict__ ccnt) {
  int w = threadIdx.x >> 6, lane = threadIdx.x & 63;
  int t = blockIdx.x * 4 + w;
  const float* xr = x + (size_t)t * DMODEL;
  double acc[NEXP];
#pragma unroll
  for (int e = 0; e < NEXP; ++e) acc[e] = 0.0;
  for (int c = lane; c < DMODEL; c += 64) {
    float xv = xr[c];
#pragma unroll
    for (int e = 0; e < NEXP; ++e) acc[e] += (double)xv * (double)rw[e*DMODEL + c];
  }
#pragma unroll
  for (int e = 0; e < NEXP; ++e) {
#pragma unroll
    for (int off = 32; off > 0; off >>= 1) acc[e] += __shfl_down(acc[e], off, 64);
  }
  if (lane == 0) {
    double best = -1e300, sec = -1e300; int bi = 0, si = 0;
#pragma unroll
    for (int e = 0; e < NEXP; ++e) {
      double v = acc[e] + (double)rb[e] + (double)noise[(size_t)t*NEXP + e] * 0.02;
      if (v > best)     { sec = best; si = bi; best = v; bi = e; }
      else if (v > sec) { sec = v; si = e; }
    }
    topk[2*t] = bi; topk[2*t+1] = si;
    int chunk = t >> 7;
    atomicAdd(&ccnt[chunk*NEXP + bi], 1);
    atomicAdd(&ccnt[chunk*NEXP + si], 1);
  }
}

// ---- K3: exclusive prefix of chunk counts (tiny) ----
__global__ void chunk_prefix(const int* __restrict__ ccnt, int* __restrict__ cbase) {
  int e = threadIdx.x;
  if (e < NEXP) {
    int run = 0;
    for (int c = 0; c < 128; ++c) { cbase[c*NEXP + e] = run; run += ccnt[c*NEXP + e]; }
  }
}

// ---- K4: capacity acceptance, final expert = max accepted, atomic compaction ----
__global__ __launch_bounds__(128) void assign_compact(const int* __restrict__ topk,
    const int* __restrict__ cbase, int* __restrict__ counts, int* __restrict__ lists) {
  int chunk = blockIdx.x, tid = threadIdx.x;
  int lane = tid & 63, w = tid >> 6;
  int t = chunk*128 + tid;
  int i0 = topk[2*t], i1 = topk[2*t+1];
  __shared__ int w0cnt[NEXP];
  unsigned long long below = (1ull << lane) - 1ull;
#pragma unroll
  for (int e = 0; e < NEXP; ++e) {
    unsigned long long bal = __ballot((i0 == e) || (i1 == e));
    if (w == 0 && lane == 0) w0cnt[e] = __popcll(bal);
  }
  __syncthreads();
  int fin = -1;
#pragma unroll
  for (int e = 0; e < NEXP; ++e) {
    bool m = (i0 == e) || (i1 == e);
    unsigned long long bal = __ballot(m);
    int rank = cbase[chunk*NEXP + e] + (w ? w0cnt[e] : 0) + __popcll(bal & below);
    if (m && rank < CAPACITY) fin = e;    // ascending e -> ends at max accepted
  }
#pragma unroll
  for (int e = 0; e < NEXP; ++e) {
    bool m = (fin == e);
    unsigned long long bal = __ballot(m);
    int c = __popcll(bal);
    if (c) {
      int leader = __ffsll((unsigned long long)bal) - 1;
      int base = 0;
      if (lane == leader) base = atomicAdd(&counts[e], c);
      base = __shfl(base, leader, 64);
      if (m) lists[e*CAP_PAD + base + __popcll(bal & below)] = t;
    }
  }
}

// ---- K5: padded counts + compact region offsets ----
__global__ void calc_offsets(const int* __restrict__ counts, int* __restrict__ offs,
                             int* __restrict__ pcnt) {
  if (threadIdx.x == 0) {
    int run = 0;
    for (int e = 0; e < NEXP; ++e) {
      offs[e] = run;
      int pc = ((counts[e] + 127) >> 7) << 7;
      pcnt[e] = pc;
      run += pc;
    }
    offs[NEXP] = run;
  }
}

// ---- K6: gather x rows -> bf16 compact per-expert regions (pad rows zeroed) ----
__global__ __launch_bounds__(128) void gather_x(const float* __restrict__ x,
    const int* __restrict__ lists, const int* __restrict__ counts,
    const int* __restrict__ offs, const int* __restrict__ pcnt, u16* __restrict__ xg) {
  int bid = blockIdx.x;
  int e = bid / CAP_PAD, r = bid % CAP_PAD;
  if (r >= pcnt[e]) return;
  unsigned long long* dst = (unsigned long long*)(xg + (size_t)(offs[e] + r) * DMODEL);
  int tid = threadIdx.x;
  if (r < counts[e]) {
    const float4* src = (const float4*)(x + (size_t)lists[e*CAP_PAD + r] * DMODEL);
#pragma unroll
    for (int i = 0; i < 2; ++i) {
      float4 v = src[tid + i*128];
      unsigned long long pk = (unsigned long long)f2bf(v.x)
                            | ((unsigned long long)f2bf(v.y) << 16)
                            | ((unsigned long long)f2bf(v.z) << 32)
                            | ((unsigned long long)f2bf(v.w) << 48);
      dst[tid + i*128] = pk;
    }
  } else {
#pragma unroll
    for (int i = 0; i < 2; ++i) dst[tid + i*128] = 0ull;
  }
}

// ---- K7: GEMM1  h = gelu(xg @ w1 + b1), bf16 out. m97 ladder structure. ----
__global__ __launch_bounds__(256) void ffn1_gemm(const u16* __restrict__ xg,
    const u16* __restrict__ w1t, const float* __restrict__ b1,
    const int* __restrict__ offs, const int* __restrict__ pcnt, u16* __restrict__ h) {
  const int BPE = 26*32;
  int bid = blockIdx.x;
  int e = bid / BPE, rem = bid % BPE;
  int mt = rem >> 5, nt = rem & 31;
  if (mt*128 >= pcnt[e]) return;
  const u16* A = xg + (size_t)offs[e] * DMODEL;          // [rows][1024]
  const u16* B = w1t + (size_t)e * DFF * DMODEL;         // [4096][1024] = B^T
  u16* H = h + (size_t)offs[e] * DFF;
  __shared__ __align__(16) u16 As[128*32];
  __shared__ __align__(16) u16 Bs[128*32];
  int tid = threadIdx.x, lane = tid & 63, w = tid >> 6;
  int m0 = mt*128, n0 = nt*128;
  int wm = (w & 1)*64, wn = (w >> 1)*64;
  int fr = lane & 15, fkb = (lane >> 4)*8;
  f32x4 acc[4][4] = {};
  for (int kt = 0; kt < DMODEL; kt += 32) {
    __syncthreads();
#pragma unroll
    for (int i = 0; i < 2; ++i) {
      int slot = i*256 + tid;
      int row = slot >> 2, kc = slot & 3;
      async_cp16(A + (size_t)(m0+row)*DMODEL + kt + kc*8, As + (size_t)(i*256 + w*64)*8);
      async_cp16(B + (size_t)(n0+row)*DMODEL + kt + kc*8, Bs + (size_t)(i*256 + w*64)*8);
    }
    __syncthreads();
    bf16x8 af[4], bfr[4];
#pragma unroll
    for (int i = 0; i < 4; ++i) af[i] = *(const bf16x8*)(As + (wm + i*16 + fr)*32 + fkb);
#pragma unroll
    for (int j = 0; j < 4; ++j) bfr[j] = *(const bf16x8*)(Bs + (wn + j*16 + fr)*32 + fkb);
#pragma unroll
    for (int i = 0; i < 4; ++i)
#pragma unroll
      for (int j = 0; j < 4; ++j)
        acc[i][j] = __builtin_amdgcn_mfma_f32_16x16x32_bf16(af[i], bfr[j], acc[i][j], 0, 0, 0);
  }
  const float* b1e = b1 + e*DFF;
#pragma unroll
  for (int j = 0; j < 4; ++j) {
    int col = n0 + wn + j*16 + (lane & 15);
    float bias = b1e[col];
#pragma unroll
    for (int i = 0; i < 4; ++i) {
#pragma unroll
      for (int r = 0; r < 4; ++r) {
        int row = m0 + wm + i*16 + (lane >> 4)*4 + r;
        float v = acc[i][j][r] + bias;
        float g = 0.5f * v * (1.0f + erff(v * 0.70710678118654752f));  // exact gelu
        H[(size_t)row*DFF + col] = f2bf(g);
      }
    }
  }
}

// ---- K8: GEMM2 (K-split x2)  out[token] += h @ w2 (+ b2 on split 0) ----
__global__ __launch_bounds__(256) void ffn2_gemm(const u16* __restrict__ h,
    const u16* __restrict__ w2t, const float* __restrict__ b2,
    const int* __restrict__ offs, const int* __restrict__ pcnt,
    const int* __restrict__ counts, const int* __restrict__ lists,
    float* __restrict__ out) {
  const int BPE = 26*8*2;
  int bid = blockIdx.x;
  int e = bid / BPE, rem = bid % BPE;
  int mt = rem >> 4, rem2 = rem & 15;
  int nt = rem2 >> 1, s = rem2 & 1;
  if (mt*128 >= pcnt[e]) return;
  int cnt = counts[e];
  const u16* A = h + (size_t)offs[e] * DFF;              // [rows][4096]
  const u16* B = w2t + (size_t)e * DMODEL * DFF;         // [1024][4096] = B^T
  __shared__ __align__(16) u16 As[128*32];
  __shared__ __align__(16) u16 Bs[128*32];
  int tid = threadIdx.x, lane = tid & 63, w = tid >> 6;
  int m0 = mt*128, n0 = nt*128;
  int wm = (w & 1)*64, wn = (w >> 1)*64;
  int fr = lane & 15, fkb = (lane >> 4)*8;
  f32x4 acc[4][4] = {};
  int k0 = s * (DFF/2), k1 = k0 + (DFF/2);
  for (int kt = k0; kt < k1; kt += 32) {
    __syncthreads();
#pragma unroll
    for (int i = 0; i < 2; ++i) {
      int slot = i*256 + tid;
      int row = slot >> 2, kc = slot & 3;
      async_cp16(A + (size_t)(m0+row)*DFF + kt + kc*8, As + (size_t)(i*256 + w*64)*8);
      async_cp16(B + (size_t)(n0+row)*DFF + kt + kc*8, Bs + (size_t)(i*256 + w*64)*8);
    }
    __syncthreads();
    bf16x8 af[4], bfr[4];
#pragma unroll
    for (int i = 0; i < 4; ++i) af[i] = *(const bf16x8*)(As + (wm + i*16 + fr)*32 + fkb);
#pragma unroll
    for (int j = 0; j < 4; ++j) bfr[j] = *(const bf16x8*)(Bs + (wn + j*16 + fr)*32 + fkb);
#pragma unroll
    for (int i = 0; i < 4; ++i)
#pragma unroll
      for (int j = 0; j < 4; ++j)
        acc[i][j] = __builtin_amdgcn_mfma_f32_16x16x32_bf16(af[i], bfr[j], acc[i][j], 0, 0, 0);
  }
  const float* b2e = b2 + e*DMODEL;
  const int* liste = lists + e*CAP_PAD;
#pragma unroll
  for (int j = 0; j < 4; ++j) {
    int col = n0 + wn + j*16 + (lane & 15);
    float bias = (s == 0) ? b2e[col] : 0.0f;
#pragma unroll
    for (int i = 0; i < 4; ++i) {
#pragma unroll
      for (int r = 0; r < 4; ++r) {
        int row = m0 + wm + i*16 + (lane >> 4)*4 + r;
        if (row < cnt) {
          int t = liste[row];
          atomicAdd(&out[(size_t)t*DMODEL + col], acc[i][j][r] + bias);
        }
      }
    }
  }
}

extern "C" void kernel_launch(void* const* d_in, const int* in_sizes, int n_in,
                              void* d_out, int out_size, void* d_ws, size_t ws_size,
                              hipStream_t stream) {
  const float* x     = (const float*)d_in[0];
  const float* noise = (const float*)d_in[1];
  const float* rw    = (const float*)d_in[2];
  const float* rb    = (const float*)d_in[3];
  const float* w1    = (const float*)d_in[4];
  const float* b1    = (const float*)d_in[5];
  const float* w2    = (const float*)d_in[6];
  const float* b2    = (const float*)d_in[7];
  float* out = (float*)d_out;
  char* ws = (char*)d_ws;

  u16* w1t   = (u16*)(ws + W1T_OFF);
  u16* w2t   = (u16*)(ws + W2T_OFF);
  u16* xg    = (u16*)(ws + XG_OFF);
  u16* hbuf  = (u16*)(ws + H_OFF);
  int* topk  = (int*)(ws + TOPK_OFF);
  int* ccnt  = (int*)(ws + CCNT_OFF);
  int* cbase = (int*)(ws + CBASE_OFF);
  int* lists = (int*)(ws + LISTS_OFF);
  int* cnts  = (int*)(ws + CNT_OFF);
  int* offs  = (int*)(ws + OFFS_OFF);
  int* pcnt  = (int*)(ws + PCNT_OFF);

  // out must start zero (unassigned tokens + atomic accumulation);
  // routing scratch (ccnt, cnts) must start zero.
  hipMemsetAsync(d_out, 0, (size_t)T_TOK * DMODEL * sizeof(float), stream);
  hipMemsetAsync(ws + CCNT_OFF, 0, ZERO_SPAN, stream);

  transpose_cvt64<<<16384, 256, 0, stream>>>(w1, w1t, w2, w2t);
  router_topk<<<T_TOK/4, 256, 0, stream>>>(x, rw, rb, noise, topk, ccnt);
  chunk_prefix<<<1, 64, 0, stream>>>(ccnt, cbase);
  assign_compact<<<128, 128, 0, stream>>>(topk, cbase, cnts, lists);
  calc_offsets<<<1, 64, 0, stream>>>(cnts, offs, pcnt);
  gather_x<<<NEXP*CAP_PAD, 128, 0, stream>>>(x, lists, cnts, offs, pcnt, xg);
  ffn1_gemm<<<NEXP*26*32, 256, 0, stream>>>(xg, w1t, b1, offs, pcnt, hbuf);
  ffn2_gemm<<<NEXP*26*8*2, 256, 0, stream>>>(hbuf, w2t, b2, offs, pcnt, cnts, lists, out);
}

// Round 3
// 880.922 us; speedup vs baseline: 1.0445x; 1.0445x over previous
//
#include <hip/hip_runtime.h>
#include <math.h>

// ---- problem constants ----
#define T_TOK   16384
#define DMODEL  1024
#define DFF     4096
#define NEXP    8
#define CAPACITY 3277            // ceil(16384*1.6/8)
#define CAP_PAD  3328            // ceil(CAPACITY/128)*128
#define MAXR    17408            // max total padded rows (16384 + 8*128)

#define FFN1_TILES (NEXP*26*32)      // 6656
#define FFN2_TILES (NEXP*26*8*2)     // 3328 (K-split x2)
#define PERSIST_BLOCKS 768           // 3 blocks/CU x 256 CU

typedef unsigned short u16;
typedef __attribute__((ext_vector_type(8))) __bf16 bf16x8;
typedef __attribute__((ext_vector_type(4))) float  f32x4;

// ---- workspace layout (bytes). Total ~312.7 MB (same footprint as R1). ----
// P0/P1 (ffn2 K-split partials) overlay w1t+xg head, both dead after ffn1.
#define W2T_OFF   0ull                  // 67108864   bf16 [E][D][DFF]   (B^T for GEMM2)
#define H_OFF     67108864ull           // 142606336  bf16 hidden [MAXR][DFF]
#define W1T_OFF   209715200ull          // 67108864   bf16 [E][DFF][D]   (B^T for GEMM1)
#define XG_OFF    276824064ull          // 35651584   bf16 gathered x [MAXR][D]
#define P0_OFF    209715200ull          // 35651584   bf16 partial s=0 (overlays w1t)
#define P1_OFF    245366784ull          // 35651584   bf16 partial s=1 (overlays w1t tail + xg head)
#define TOPK_OFF  312475648ull          // 131072
#define QC_OFF    312606720ull          // 8  (two queue counters)   [zeroed]
#define CCNT_OFF  312606728ull          // 4096                      [zeroed]
#define CNT_OFF   312610824ull          // 32                        [zeroed]
#define CBASE_OFF 312610856ull          // 4096
#define LISTS_OFF 312614952ull          // 106496
#define OFFS_OFF  312721448ull          // 36
#define PCNT_OFF  312721484ull          // 32   -> end 312721516
#define ZERO_OFF  QC_OFF
#define ZERO_SPAN (312610856ull - QC_OFF)   // qc + ccnt + cnt

__device__ __forceinline__ u16 f2bf(float x) {   // round-to-nearest-even f32->bf16
  union { float f; unsigned u; } v; v.f = x;
  unsigned r = v.u + 0x7fffu + ((v.u >> 16) & 1u);
  return (u16)(r >> 16);
}
__device__ __forceinline__ float bf2f(u16 x) {
  union { unsigned u; float f; } v; v.u = ((unsigned)x) << 16; return v.f;
}

__device__ __forceinline__ void async_cp16(const void* g, void* l) {
  // global -> LDS direct, 16B/lane. LDS dest is wave-uniform base + lane*16.
  __builtin_amdgcn_global_load_lds((const __attribute__((address_space(1))) void*)g,
                                   (__attribute__((address_space(3))) void*)l,
                                   16, 0, 0);
}

// ---- K1: fp32->bf16 transpose-convert, 64x64 tiles, vectorized both sides ----
__global__ __launch_bounds__(256) void transpose_cvt64(const float* __restrict__ w1,
    u16* __restrict__ w1t, const float* __restrict__ w2, u16* __restrict__ w2t) {
  int bid = blockIdx.x;
  const float* src; u16* dst; int R, C;
  if (bid < 8192) { src = w1; dst = w1t; R = 1024; C = 4096; }
  else            { src = w2; dst = w2t; R = 4096; C = 1024; bid -= 8192; }
  int tilesC = C >> 6;
  int per_e = (R >> 6) * tilesC;
  int e = bid / per_e, rem = bid % per_e;
  int rt = rem / tilesC, ct = rem % tilesC;
  const float* s = src + (size_t)e*R*C + (size_t)(rt*64)*C + ct*64;
  u16* d = dst + (size_t)e*R*C + (size_t)(ct*64)*R + rt*64;
  __shared__ float tile[64][65];
  int t = threadIdx.x, r0 = t >> 4, c4 = (t & 15) * 4;
#pragma unroll
  for (int i = 0; i < 4; ++i) {
    int row = r0 + i*16;
    float4 v = *(const float4*)(s + (size_t)row*C + c4);
    tile[row][c4] = v.x; tile[row][c4+1] = v.y; tile[row][c4+2] = v.z; tile[row][c4+3] = v.w;
  }
  __syncthreads();
#pragma unroll
  for (int k = 0; k < 4; ++k) {
    int q = k*256 + t;
    int c = q >> 4, g = q & 15;
    ushort4 o;
    o.x = f2bf(tile[g*4+0][c]); o.y = f2bf(tile[g*4+1][c]);
    o.z = f2bf(tile[g*4+2][c]); o.w = f2bf(tile[g*4+3][c]);
    *(ushort4*)(d + (size_t)c*R + g*4) = o;
  }
}

// ---- K2: router logits + noise, top-2 (fp64 accum), fused chunk counts ----
__global__ __launch_bounds__(256) void router_topk(const float* __restrict__ x,
    const float* __restrict__ rw, const float* __restrict__ rb,
    const float* __restrict__ noise, int* __restrict__ topk, int* __restrict__ ccnt) {
  int w = threadIdx.x >> 6, lane = threadIdx.x & 63;
  int t = blockIdx.x * 4 + w;
  const float* xr = x + (size_t)t * DMODEL;
  double acc[NEXP];
#pragma unroll
  for (int e = 0; e < NEXP; ++e) acc[e] = 0.0;
  for (int c = lane; c < DMODEL; c += 64) {
    float xv = xr[c];
#pragma unroll
    for (int e = 0; e < NEXP; ++e) acc[e] += (double)xv * (double)rw[e*DMODEL + c];
  }
#pragma unroll
  for (int e = 0; e < NEXP; ++e) {
#pragma unroll
    for (int off = 32; off > 0; off >>= 1) acc[e] += __shfl_down(acc[e], off, 64);
  }
  if (lane == 0) {
    double best = -1e300, sec = -1e300; int bi = 0, si = 0;
#pragma unroll
    for (int e = 0; e < NEXP; ++e) {
      double v = acc[e] + (double)rb[e] + (double)noise[(size_t)t*NEXP + e] * 0.02;
      if (v > best)     { sec = best; si = bi; best = v; bi = e; }
      else if (v > sec) { sec = v; si = e; }
    }
    topk[2*t] = bi; topk[2*t+1] = si;
    int chunk = t >> 7;
    atomicAdd(&ccnt[chunk*NEXP + bi], 1);
    atomicAdd(&ccnt[chunk*NEXP + si], 1);
  }
}

// ---- K3: exclusive prefix of chunk counts (tiny) ----
__global__ void chunk_prefix(const int* __restrict__ ccnt, int* __restrict__ cbase) {
  int e = threadIdx.x;
  if (e < NEXP) {
    int run = 0;
    for (int c = 0; c < 128; ++c) { cbase[c*NEXP + e] = run; run += ccnt[c*NEXP + e]; }
  }
}

// ---- K4: capacity acceptance, final expert = max accepted, atomic compaction ----
__global__ __launch_bounds__(128) void assign_compact(const int* __restrict__ topk,
    const int* __restrict__ cbase, int* __restrict__ counts, int* __restrict__ lists) {
  int chunk = blockIdx.x, tid = threadIdx.x;
  int lane = tid & 63, w = tid >> 6;
  int t = chunk*128 + tid;
  int i0 = topk[2*t], i1 = topk[2*t+1];
  __shared__ int w0cnt[NEXP];
  unsigned long long below = (1ull << lane) - 1ull;
#pragma unroll
  for (int e = 0; e < NEXP; ++e) {
    unsigned long long bal = __ballot((i0 == e) || (i1 == e));
    if (w == 0 && lane == 0) w0cnt[e] = __popcll(bal);
  }
  __syncthreads();
  int fin = -1;
#pragma unroll
  for (int e = 0; e < NEXP; ++e) {
    bool m = (i0 == e) || (i1 == e);
    unsigned long long bal = __ballot(m);
    int rank = cbase[chunk*NEXP + e] + (w ? w0cnt[e] : 0) + __popcll(bal & below);
    if (m && rank < CAPACITY) fin = e;    // ascending e -> ends at max accepted
  }
#pragma unroll
  for (int e = 0; e < NEXP; ++e) {
    bool m = (fin == e);
    unsigned long long bal = __ballot(m);
    int c = __popcll(bal);
    if (c) {
      int leader = __ffsll((unsigned long long)bal) - 1;
      int base = 0;
      if (lane == leader) base = atomicAdd(&counts[e], c);
      base = __shfl(base, leader, 64);
      if (m) lists[e*CAP_PAD + base + __popcll(bal & below)] = t;
    }
  }
}

// ---- K5: padded counts + compact region offsets ----
__global__ void calc_offsets(const int* __restrict__ counts, int* __restrict__ offs,
                             int* __restrict__ pcnt) {
  if (threadIdx.x == 0) {
    int run = 0;
    for (int e = 0; e < NEXP; ++e) {
      offs[e] = run;
      int pc = ((counts[e] + 127) >> 7) << 7;
      pcnt[e] = pc;
      run += pc;
    }
    offs[NEXP] = run;
  }
}

// ---- K6: gather x rows -> bf16 compact per-expert regions (pad rows zeroed) ----
__global__ __launch_bounds__(128) void gather_x(const float* __restrict__ x,
    const int* __restrict__ lists, const int* __restrict__ counts,
    const int* __restrict__ offs, const int* __restrict__ pcnt, u16* __restrict__ xg) {
  int bid = blockIdx.x;
  int e = bid / CAP_PAD, r = bid % CAP_PAD;
  if (r >= pcnt[e]) return;
  unsigned long long* dst = (unsigned long long*)(xg + (size_t)(offs[e] + r) * DMODEL);
  int tid = threadIdx.x;
  if (r < counts[e]) {
    const float4* src = (const float4*)(x + (size_t)lists[e*CAP_PAD + r] * DMODEL);
#pragma unroll
    for (int i = 0; i < 2; ++i) {
      float4 v = src[tid + i*128];
      unsigned long long pk = (unsigned long long)f2bf(v.x)
                            | ((unsigned long long)f2bf(v.y) << 16)
                            | ((unsigned long long)f2bf(v.z) << 32)
                            | ((unsigned long long)f2bf(v.w) << 48);
      dst[tid + i*128] = pk;
    }
  } else {
#pragma unroll
    for (int i = 0; i < 2; ++i) dst[tid + i*128] = 0ull;
  }
}

// ---- K7: GEMM1  h = gelu(xg @ w1 + b1), persistent blocks + atomic tile queue ----
__global__ __launch_bounds__(256, 3) void ffn1_gemm(const u16* __restrict__ xg,
    const u16* __restrict__ w1t, const float* __restrict__ b1,
    const int* __restrict__ offs, const int* __restrict__ pcnt,
    u16* __restrict__ h, int* __restrict__ qc) {
  __shared__ __align__(16) u16 As[128*32];
  __shared__ __align__(16) u16 Bs[128*32];
  __shared__ int s_tile;
  int tid = threadIdx.x, lane = tid & 63, w = tid >> 6;
  int wm = (w & 1)*64, wn = (w >> 1)*64;
  int fr = lane & 15, fkb = (lane >> 4)*8, q4 = (lane >> 4)*4;
  for (;;) {
    __syncthreads();
    if (tid == 0) s_tile = atomicAdd(qc, 1);
    __syncthreads();
    int tile = s_tile;
    if (tile >= FFN1_TILES) return;
    int e = tile / 832, rem = tile % 832;     // 832 = 26*32
    int mt = rem >> 5, nt = rem & 31;
    if (mt*128 >= pcnt[e]) continue;
    const u16* A = xg + (size_t)offs[e] * DMODEL;
    const u16* B = w1t + (size_t)e * DFF * DMODEL;
    u16* H = h + (size_t)offs[e] * DFF;
    int m0 = mt*128, n0 = nt*128;
    f32x4 acc[4][4] = {};
    for (int kt = 0; kt < DMODEL; kt += 32) {
      __syncthreads();
#pragma unroll
      for (int i = 0; i < 2; ++i) {
        int slot = i*256 + tid;
        int row = slot >> 2, kc = slot & 3;
        async_cp16(A + (size_t)(m0+row)*DMODEL + kt + kc*8, As + (size_t)(i*256 + w*64)*8);
        async_cp16(B + (size_t)(n0+row)*DMODEL + kt + kc*8, Bs + (size_t)(i*256 + w*64)*8);
      }
      __syncthreads();
      bf16x8 af[4], bfr[4];
#pragma unroll
      for (int i = 0; i < 4; ++i) af[i] = *(const bf16x8*)(As + (wm + i*16 + fr)*32 + fkb);
#pragma unroll
      for (int j = 0; j < 4; ++j) bfr[j] = *(const bf16x8*)(Bs + (wn + j*16 + fr)*32 + fkb);
#pragma unroll
      for (int i = 0; i < 4; ++i)
#pragma unroll
        for (int j = 0; j < 4; ++j)
          acc[i][j] = __builtin_amdgcn_mfma_f32_16x16x32_bf16(af[i], bfr[j], acc[i][j], 0, 0, 0);
    }
    const float* b1e = b1 + e*DFF;
#pragma unroll
    for (int j = 0; j < 4; ++j) {
      int col = n0 + wn + j*16 + fr;
      float bias = b1e[col];
#pragma unroll
      for (int i = 0; i < 4; ++i) {
#pragma unroll
        for (int r = 0; r < 4; ++r) {
          int row = m0 + wm + i*16 + q4 + r;
          float v = acc[i][j][r] + bias;
          // tanh-GELU: |value err| <= ~1e-3 vs exact erf form
          float u = v * (0.79788456f + 0.035677408f * v * v);
          u = fminf(fmaxf(u, -9.0f), 9.0f);
          float g = __fdividef(v, 1.0f + __expf(-2.0f * u));
          H[(size_t)row*DFF + col] = f2bf(g);
        }
      }
    }
  }
}

// ---- K8: GEMM2 (K-split x2), persistent queue, plain bf16 partial stores ----
__global__ __launch_bounds__(256, 3) void ffn2_gemm(const u16* __restrict__ h,
    const u16* __restrict__ w2t, const int* __restrict__ offs,
    const int* __restrict__ pcnt, u16* __restrict__ p0, u16* __restrict__ p1,
    int* __restrict__ qc) {
  __shared__ __align__(16) u16 As[128*32];
  __shared__ __align__(16) u16 Bs[128*32];
  __shared__ int s_tile;
  int tid = threadIdx.x, lane = tid & 63, w = tid >> 6;
  int wm = (w & 1)*64, wn = (w >> 1)*64;
  int fr = lane & 15, fkb = (lane >> 4)*8, q4 = (lane >> 4)*4;
  for (;;) {
    __syncthreads();
    if (tid == 0) s_tile = atomicAdd(qc, 1);
    __syncthreads();
    int tile = s_tile;
    if (tile >= FFN2_TILES) return;
    int e = tile / 416, rem = tile % 416;     // 416 = 26*8*2
    int mt = rem >> 4, r2 = rem & 15;
    int nt = r2 >> 1, s = r2 & 1;
    if (mt*128 >= pcnt[e]) continue;
    const u16* A = h + (size_t)offs[e] * DFF;
    const u16* B = w2t + (size_t)e * DMODEL * DFF;
    int m0 = mt*128, n0 = nt*128;
    f32x4 acc[4][4] = {};
    int k0 = s * (DFF/2), k1 = k0 + (DFF/2);
    for (int kt = k0; kt < k1; kt += 32) {
      __syncthreads();
#pragma unroll
      for (int i = 0; i < 2; ++i) {
        int slot = i*256 + tid;
        int row = slot >> 2, kc = slot & 3;
        async_cp16(A + (size_t)(m0+row)*DFF + kt + kc*8, As + (size_t)(i*256 + w*64)*8);
        async_cp16(B + (size_t)(n0+row)*DFF + kt + kc*8, Bs + (size_t)(i*256 + w*64)*8);
      }
      __syncthreads();
      bf16x8 af[4], bfr[4];
#pragma unroll
      for (int i = 0; i < 4; ++i) af[i] = *(const bf16x8*)(As + (wm + i*16 + fr)*32 + fkb);
#pragma unroll
      for (int j = 0; j < 4; ++j) bfr[j] = *(const bf16x8*)(Bs + (wn + j*16 + fr)*32 + fkb);
#pragma unroll
      for (int i = 0; i < 4; ++i)
#pragma unroll
        for (int j = 0; j < 4; ++j)
          acc[i][j] = __builtin_amdgcn_mfma_f32_16x16x32_bf16(af[i], bfr[j], acc[i][j], 0, 0, 0);
    }
    u16* P = s ? p1 : p0;
#pragma unroll
    for (int j = 0; j < 4; ++j) {
      int col = n0 + wn + j*16 + fr;
#pragma unroll
      for (int i = 0; i < 4; ++i) {
#pragma unroll
        for (int r = 0; r < 4; ++r) {
          int prow = offs[e] + m0 + wm + i*16 + q4 + r;
          P[(size_t)prow*DMODEL + col] = f2bf(acc[i][j][r]);
        }
      }
    }
  }
}

// ---- K9: reduce K-split partials + bias, scatter to token rows ----
__global__ __launch_bounds__(256) void ffn2_reduce(const u16* __restrict__ p0,
    const u16* __restrict__ p1, const float* __restrict__ b2,
    const int* __restrict__ offs, const int* __restrict__ counts,
    const int* __restrict__ lists, float* __restrict__ out) {
  int r = blockIdx.x;
  int e = -1;
#pragma unroll
  for (int i = 0; i < NEXP; ++i) if (r >= offs[i] && r < offs[i+1]) e = i;
  if (e < 0) return;
  int local = r - offs[e];
  if (local >= counts[e]) return;   // padded slot: no token
  int tok = lists[e*CAP_PAD + local];
  int c = threadIdx.x * 4;
  ushort4 a = *(const ushort4*)(p0 + (size_t)r*DMODEL + c);
  ushort4 b = *(const ushort4*)(p1 + (size_t)r*DMODEL + c);
  const float* bb = b2 + e*DMODEL + c;
  float4 o;
  o.x = bf2f(a.x) + bf2f(b.x) + bb[0];
  o.y = bf2f(a.y) + bf2f(b.y) + bb[1];
  o.z = bf2f(a.z) + bf2f(b.z) + bb[2];
  o.w = bf2f(a.w) + bf2f(b.w) + bb[3];
  *(float4*)(out + (size_t)tok*DMODEL + c) = o;
}

extern "C" void kernel_launch(void* const* d_in, const int* in_sizes, int n_in,
                              void* d_out, int out_size, void* d_ws, size_t ws_size,
                              hipStream_t stream) {
  const float* x     = (const float*)d_in[0];
  const float* noise = (const float*)d_in[1];
  const float* rw    = (const float*)d_in[2];
  const float* rb    = (const float*)d_in[3];
  const float* w1    = (const float*)d_in[4];
  const float* b1    = (const float*)d_in[5];
  const float* w2    = (const float*)d_in[6];
  const float* b2    = (const float*)d_in[7];
  float* out = (float*)d_out;
  char* ws = (char*)d_ws;

  u16* w2t   = (u16*)(ws + W2T_OFF);
  u16* hbuf  = (u16*)(ws + H_OFF);
  u16* w1t   = (u16*)(ws + W1T_OFF);
  u16* xg    = (u16*)(ws + XG_OFF);
  u16* p0    = (u16*)(ws + P0_OFF);
  u16* p1    = (u16*)(ws + P1_OFF);
  int* topk  = (int*)(ws + TOPK_OFF);
  int* qc    = (int*)(ws + QC_OFF);
  int* ccnt  = (int*)(ws + CCNT_OFF);
  int* cnts  = (int*)(ws + CNT_OFF);
  int* cbase = (int*)(ws + CBASE_OFF);
  int* lists = (int*)(ws + LISTS_OFF);
  int* offs  = (int*)(ws + OFFS_OFF);
  int* pcnt  = (int*)(ws + PCNT_OFF);

  // out must start zero (dropped tokens); queue counters + routing counts zero.
  hipMemsetAsync(d_out, 0, (size_t)T_TOK * DMODEL * sizeof(float), stream);
  hipMemsetAsync(ws + ZERO_OFF, 0, ZERO_SPAN, stream);

  transpose_cvt64<<<16384, 256, 0, stream>>>(w1, w1t, w2, w2t);
  router_topk<<<T_TOK/4, 256, 0, stream>>>(x, rw, rb, noise, topk, ccnt);
  chunk_prefix<<<1, 64, 0, stream>>>(ccnt, cbase);
  assign_compact<<<128, 128, 0, stream>>>(topk, cbase, cnts, lists);
  calc_offsets<<<1, 64, 0, stream>>>(cnts, offs, pcnt);
  gather_x<<<NEXP*CAP_PAD, 128, 0, stream>>>(x, lists, cnts, offs, pcnt, xg);
  ffn1_gemm<<<PERSIST_BLOCKS, 256, 0, stream>>>(xg, w1t, b1, offs, pcnt, hbuf, qc);
  ffn2_gemm<<<PERSIST_BLOCKS, 256, 0, stream>>>(hbuf, w2t, offs, pcnt, p0, p1, qc + 1);
  ffn2_reduce<<<MAXR, 256, 0, stream>>>(p0, p1, b2, offs, cnts, lists, out);
}